// Round 4
// baseline (245.141 us; speedup 1.0000x reference)
//
#include <hip/hip_runtime.h>

#define LOG2E 1.44269504088896340736f
#define LN2   0.69314718055994530942f

typedef short bf8 __attribute__((ext_vector_type(8)));   // 8 bf16 = one 16x16x32 A/B frag (4 VGPRs)
typedef float f4  __attribute__((ext_vector_type(4)));   // 4 f32  = one 16x16 C/D frag

static __device__ __forceinline__ unsigned short f2bf_rne(float f) {
    unsigned u = __float_as_uint(f);
    u += 0x7FFFu + ((u >> 16) & 1u);
    return (unsigned short)(u >> 16);
}
// pack two f32 -> two bf16 (truncation; same numerics as all passing rounds)
static __device__ __forceinline__ unsigned pack_bf_trunc(float lo, float hi) {
    return __builtin_amdgcn_perm(__float_as_uint(hi), __float_as_uint(lo), 0x07060302u);
}

// ============================================================================
// Kernel 1: per-(batch, 64-step chunk) operator product, COLUMN-SLICED:
// one 4-wave block per chunk; wave w owns columns [16w, 16w+16) of P.
// Columns evolve independently (P_new[:,n] = D * M^T * P[:,n]), so no
// cross-wave communication and no barriers; d is computed redundantly per
// wave into a private LDS slice.
//
//   Op_t = mask_t ? D_t * M^T : I,  D_t = diag(exp(em_t) * 2^-7), M = exp(tr)
//   P_c  = Op_{t0+63} ... Op_{t0}   (64x64), dumped bf16 as P^T.
//
// Per wave/step: 8 MFMA (16x16x32) + ~50 VALU, ~90 VGPRs -> fits the 128-reg
// budget of waves_per_eu(4): pure arch VGPRs, no v_accvgpr move traffic
// (round-3's VGPR_Count=60 + 320 VALU/step/wave was AGPR-split bloat from
// the lax 256-reg budget).
//
// Layout (verified r3, absmax 0): B-frag bfr[kt][j] = P[32kt+8q+j][16w+nl];
// MFMA output tile mt maps to global rows g(mt, m=4q+r) = 32(mt>>1)+8q+
// 4(mt&1)+r, so tile mt's scaled/packed output IS dword-half (mt&1) of
// bfr[mt>>1] in the same lane. Row permutation folded into A-frags at setup.
// ============================================================================
__global__ __attribute__((amdgpu_flat_work_group_size(256, 256), amdgpu_waves_per_eu(4)))
void crf_scan(const int* __restrict__ yg, const float* __restrict__ em,
              const float* __restrict__ tr, unsigned short* __restrict__ Pg)
{
    constexpr int T = 1024;
    const int c = blockIdx.x, b = blockIdx.y;
    const int tid = threadIdx.x;
    const int w = tid >> 6;                       // wave = owned column tile nt
    const int lane = tid & 63, nl = lane & 15, q = lane >> 4;

    __shared__ __align__(16) float d_sh[4][64];   // per-wave private slice

    // ---- A-fragments of M^T with permuted rows (constant):
    //      afr[mt][ka], elem j: A[m=nl][k=8q+j of K-tile ka]
    //        = exp(tr[(32ka+8q+j)*64 + g(mt,nl)])
    bf8 afr[4][2];
    #pragma unroll
    for (int mt = 0; mt < 4; ++mt) {
        const int g = 32 * (mt >> 1) + 8 * (nl >> 2) + 4 * (mt & 1) + (nl & 3);
        #pragma unroll
        for (int ka = 0; ka < 2; ++ka) {
            bf8 v;
            #pragma unroll
            for (int j = 0; j < 8; ++j) {
                const int k = 32 * ka + 8 * q + j;
                v[j] = (short)f2bf_rne(exp2f(tr[k * 64 + g] * LOG2E));
            }
            afr[mt][ka] = v;
        }
    }

    // ---- P[:, 16w..16w+15] = I-slice: bfr[kt][j] = (32kt+8q+j == 16w+nl) ----
    bf8 bfr[2];
    #pragma unroll
    for (int kt = 0; kt < 2; ++kt) {
        bf8 v;
        #pragma unroll
        for (int j = 0; j < 8; ++j)
            v[j] = (short)((32 * kt + 8 * q + j == 16 * w + nl) ? 0x3F80 : 0);
        bfr[kt] = v;
    }

    const int t0 = 1 + 64 * c;
    const int nsteps = (c == 15) ? 63 : 64;
    const float* emb = em + (size_t)b * T * 64;

    int tl = t0 + lane; if (tl > T - 1) tl = T - 1;
    const int yvl = yg[b * T + tl];
    const unsigned long long msk = __ballot(lane < nsteps && yvl != 0);

    float ldc = emb[t0 * 64 + lane];              // emission prefetch (1 deep)
    for (int s = 0; s < nsteps; ++s) {
        int tn = t0 + s + 1; if (tn > T - 1) tn = T - 1;
        const float ldn = emb[tn * 64 + lane];
        if ((msk >> s) & 1ull) {                  // wave-uniform; active ~98.4%
            d_sh[w][lane] = exp2f(ldc * LOG2E - 7.0f);   // d[state=lane]
            // d quads for tile mt regs r=0..3: rows g(mt,4q+r) ->
            // d_sh[w][32(mt>>1) + 4(mt&1) + 8q + r]  (broadcast f4; per-wave
            // DS pipe is in-order, so write->read needs no barrier)
            f4 dq[4];
            #pragma unroll
            for (int mt = 0; mt < 4; ++mt)
                dq[mt] = *(const f4*)&d_sh[w][32 * (mt >> 1) + 4 * (mt & 1) + 8 * q];
            // 4 output tiles, each a 2-deep K=64 chain on my column slice
            f4 acc[4];
            #pragma unroll
            for (int mt = 0; mt < 4; ++mt) {
                f4 a = __builtin_amdgcn_mfma_f32_16x16x32_bf16(
                           afr[mt][0], bfr[0], (f4)(0.0f), 0, 0, 0);
                acc[mt] = __builtin_amdgcn_mfma_f32_16x16x32_bf16(
                           afr[mt][1], bfr[1], a, 0, 0, 0);
            }
            // scale rows by d, pack: tile mt -> bfr[mt>>1], dword-half mt&1
            #pragma unroll
            for (int kt = 0; kt < 2; ++kt) {
                union { uint4 u; bf8 v8; } wv;
                wv.u.x = pack_bf_trunc(acc[2*kt  ][0] * dq[2*kt  ][0],
                                       acc[2*kt  ][1] * dq[2*kt  ][1]);
                wv.u.y = pack_bf_trunc(acc[2*kt  ][2] * dq[2*kt  ][2],
                                       acc[2*kt  ][3] * dq[2*kt  ][3]);
                wv.u.z = pack_bf_trunc(acc[2*kt+1][0] * dq[2*kt+1][0],
                                       acc[2*kt+1][1] * dq[2*kt+1][1]);
                wv.u.w = pack_bf_trunc(acc[2*kt+1][2] * dq[2*kt+1][2],
                                       acc[2*kt+1][3] * dq[2*kt+1][3]);
                bfr[kt] = wv.v8;
            }
        }
        ldc = ldn;
    }

    // ---- dump my P^T slice: Pg[(b*16+c)*4096 + n*64 + i] = P_c[i][n],
    //      n = 16w+nl, i = 32kt+8q+j (j contiguous -> 16B stores) ----
    unsigned short* pg = Pg + ((size_t)(b * 16 + c) << 12);
    #pragma unroll
    for (int kt = 0; kt < 2; ++kt)
        *(uint4*)(pg + (16 * w + nl) * 64 + 32 * kt + 8 * q) =
            *(const uint4*)&bfr[kt];
}

// ============================================================================
// Kernel 2: per-batch combine, 4 waves/block (unchanged from round-3).
//   wave 0 : v = P_15 ... P_0 * exp(e0 - M0) with 1-chunk-ahead double-buffered
//            P prefetch, exact-pow2 re-centering per chunk.
//   waves 1-3 : gather scores (emission + transition) + masked-step count.
// ============================================================================
__global__ __attribute__((amdgpu_flat_work_group_size(256, 256)))
void crf_combine(const int* __restrict__ yg, const float* __restrict__ em,
                 const float* __restrict__ tr, const unsigned short* __restrict__ Pg,
                 float* __restrict__ out)
{
    constexpr int T = 1024;
    const int b = blockIdx.x, tid = threadIdx.x;
    const int w = tid >> 6, j = tid & 63;

    __shared__ __align__(16) float v_sh[64];
    __shared__ float red[3][4];

    float ep = 0.f, tp = 0.f; int cnt = 0;
    float v = 0.f, L = 0.f, vs = 0.f;

    if (w == 0) {
        const float e0 = em[(size_t)b * T * 64 + j];
        float M0 = e0;
        #pragma unroll
        for (int o = 32; o > 0; o >>= 1) M0 = fmaxf(M0, __shfl_xor(M0, o, 64));
        v = exp2f((e0 - M0) * LOG2E);
        L = M0;

        const unsigned short* row = Pg + ((size_t)(b * 16) << 12) + j * 64; // col j of P_c
        uint4 pA[8], pB[8];
        #pragma unroll
        for (int r = 0; r < 8; ++r) pA[r] = *(const uint4*)(row + r * 8);

#define CHUNK_STEP(CUR, NXT, CIDX)                                                 \
        do {                                                                       \
            if ((CIDX) + 1 < 16) {  /* prefetch next chunk: independent of v */    \
                const unsigned short* rn = row + ((size_t)((CIDX) + 1) << 12);     \
                _Pragma("unroll")                                                  \
                for (int r = 0; r < 8; ++r) NXT[r] = *(const uint4*)(rn + r * 8);  \
            }                                                                      \
            v_sh[j] = v;                            /* single wave: in-order DS */ \
            float s0 = 0.f, s1 = 0.f, s2 = 0.f, s3 = 0.f;                          \
            _Pragma("unroll")                                                      \
            for (int r = 0; r < 8; ++r) {                                          \
                const uint4 qq = CUR[r];                                           \
                const float* vp = &v_sh[r * 8];                                    \
                s0 = fmaf(__uint_as_float(qq.x << 16),         vp[0], s0);         \
                s1 = fmaf(__uint_as_float(qq.x & 0xFFFF0000u), vp[1], s1);         \
                s2 = fmaf(__uint_as_float(qq.y << 16),         vp[2], s2);         \
                s3 = fmaf(__uint_as_float(qq.y & 0xFFFF0000u), vp[3], s3);         \
                s0 = fmaf(__uint_as_float(qq.z << 16),         vp[4], s0);         \
                s1 = fmaf(__uint_as_float(qq.z & 0xFFFF0000u), vp[5], s1);         \
                s2 = fmaf(__uint_as_float(qq.w << 16),         vp[6], s2);         \
                s3 = fmaf(__uint_as_float(qq.w & 0xFFFF0000u), vp[7], s3);         \
            }                                                                      \
            float s = (s0 + s1) + (s2 + s3);                                       \
            const unsigned sb =                                                    \
                (unsigned)__builtin_amdgcn_readlane((int)__float_as_uint(s), 0);   \
            const int ef = (int)((sb >> 23) & 0xFF);                               \
            if (ef > 0 && ef < 255 && ef != 127) {  /* exact-pow2 re-center */     \
                const int E = ef - 127;                                            \
                s *= __uint_as_float((unsigned)(127 - E) << 23);                   \
                L += (float)E * LN2;                                               \
            }                                                                      \
            v = s;                                                                 \
        } while (0)

        for (int cc = 0; cc < 16; cc += 2) {
            CHUNK_STEP(pA, pB, cc);
            CHUNK_STEP(pB, pA, cc + 1);
        }
#undef CHUNK_STEP

        vs = v;
        #pragma unroll
        for (int o = 32; o > 0; o >>= 1) vs += __shfl_xor(vs, o, 64);
    } else {
        // ---- scores + unmasked-step count, waves 1..3 (stride 192 over t) ----
        const int* yb = yg + b * T;
        const int wt = tid - 64;                      // 0..191
        for (int t = 1 + wt; t < T; t += 192) {
            const int yt = yb[t];
            if (yt != 0) {
                ++cnt;
                tp += tr[yb[t - 1] * 64 + yt];
                ep += em[((size_t)b * T + t) * 64 + yt];
            }
        }
        if (tid == 64) {
            const int y0 = yb[0];
            if (y0 != 0) ep += em[(size_t)b * T * 64 + y0];
        }
        #pragma unroll
        for (int o = 32; o > 0; o >>= 1) {
            ep  += __shfl_xor(ep, o, 64);
            tp  += __shfl_xor(tp, o, 64);
            cnt += __shfl_xor(cnt, o, 64);
        }
        if (j == 0) { red[0][w] = ep; red[1][w] = tp; red[2][w] = (float)cnt; }
    }
    __syncthreads();

    if (tid == 0) {
        const float eps = red[0][1] + red[0][2] + red[0][3];
        const float tps = red[1][1] + red[1][2] + red[1][3];
        const float cs  = red[2][1] + red[2][2] + red[2][3];
        const float logz = L + 7.0f * LN2 * cs + __log2f(vs) * LN2;
        atomicAdd(out, (eps + tps - logz) * (-1.0f / 256.0f));
    }
}

extern "C" void kernel_launch(void* const* d_in, const int* in_sizes, int n_in,
                              void* d_out, int out_size, void* d_ws, size_t ws_size,
                              hipStream_t stream) {
    const int*   y  = (const int*)d_in[0];
    const float* em = (const float*)d_in[1];
    const float* tr = (const float*)d_in[2];
    float* out = (float*)d_out;
    unsigned short* Pg = (unsigned short*)d_ws;   // needs 256*16*4096*2 = 32 MB

    hipMemsetAsync(out, 0, sizeof(float), stream);
    crf_scan<<<dim3(16, 256), dim3(256), 0, stream>>>(y, em, tr, Pg);
    crf_combine<<<dim3(256), dim3(256), 0, stream>>>(y, em, tr, Pg, out);
}

// Round 5
// 225.688 us; speedup vs baseline: 1.0862x; 1.0862x over previous
//
#include <hip/hip_runtime.h>

#define LOG2E 1.44269504088896340736f
#define LN2   0.69314718055994530942f

typedef short bf8 __attribute__((ext_vector_type(8)));   // 8 bf16 = one 16x16x32 A/B frag (4 VGPRs)
typedef float f4  __attribute__((ext_vector_type(4)));   // 4 f32  = one 16x16 C/D frag
typedef float f2  __attribute__((ext_vector_type(2)));   // packed f32 pair -> v_pk_mul_f32

static __device__ __forceinline__ unsigned short f2bf_rne(float f) {
    unsigned u = __float_as_uint(f);
    u += 0x7FFFu + ((u >> 16) & 1u);
    return (unsigned short)(u >> 16);
}
// pack two f32 -> two bf16 (truncation; same numerics as all passing rounds)
static __device__ __forceinline__ unsigned pack_bf_trunc(float lo, float hi) {
    return __builtin_amdgcn_perm(__float_as_uint(hi), __float_as_uint(lo), 0x07060302u);
}

// ============================================================================
// Kernel 1: per-(batch, 64-step chunk) operator product, P in registers,
// 16x16x32 bf16 MFMA, TWO waves per chunk (wave w owns column tiles
// nt = 2w, 2w+1). Columns evolve independently (P_new[:,n] = D*M^T*P[:,n]):
// no cross-wave traffic, no barriers; d computed per-wave into a private
// LDS slice. 2x the schedulable waves of round-3 (overlap VALU pack of one
// wave with MFMAs of another) at round-3's low per-step VALU structure.
//
//   Op_t = mask_t ? D_t * M^T : I,  D_t = diag(exp(em_t) * 2^-7), M = exp(tr)
//   P_c  = Op_{t0+63} ... Op_{t0}   (64x64), dumped bf16 as P^T.
//
// Layout (verified r3/r4, absmax 0): B-frag bfr[kt][u][j] = P[32kt+8q+j][n],
// n = 16*(2w+u)+nl. MFMA output tile mt maps to global rows
// g(mt, m=4q+r) = 32(mt>>1)+8q+4(mt&1)+r, so tile mt's scaled/packed output
// IS dword-half (mt&1) of bfr[mt>>1][u] in the same lane; the row
// permutation is folded into the A-fragments at setup (free).
// Diag-scale uses <2 x float> multiplies -> v_pk_mul_f32 (halves scale VALU).
// ============================================================================
__global__ __attribute__((amdgpu_flat_work_group_size(128, 128), amdgpu_waves_per_eu(2, 4)))
void crf_scan(const int* __restrict__ yg, const float* __restrict__ em,
              const float* __restrict__ tr, unsigned short* __restrict__ Pg)
{
    constexpr int T = 1024;
    const int c = blockIdx.x, b = blockIdx.y;
    const int tid = threadIdx.x;
    const int w = tid >> 6;                       // wave: owns nt = 2w, 2w+1
    const int lane = tid & 63, nl = lane & 15, q = lane >> 4;

    __shared__ __align__(16) float d_sh[2][64];   // per-wave private slice

    // ---- A-fragments of M^T with permuted rows (constant):
    //      afr[mt][ka], elem j: A[m=nl][k=8q+j of K-tile ka]
    //        = exp(tr[(32ka+8q+j)*64 + g(mt,nl)])
    bf8 afr[4][2];
    #pragma unroll
    for (int mt = 0; mt < 4; ++mt) {
        const int g = 32 * (mt >> 1) + 8 * (nl >> 2) + 4 * (mt & 1) + (nl & 3);
        #pragma unroll
        for (int ka = 0; ka < 2; ++ka) {
            bf8 v;
            #pragma unroll
            for (int j = 0; j < 8; ++j) {
                const int k = 32 * ka + 8 * q + j;
                v[j] = (short)f2bf_rne(exp2f(tr[k * 64 + g] * LOG2E));
            }
            afr[mt][ka] = v;
        }
    }

    // ---- P[:, my 32 cols] = I-slice: bfr[kt][u][j] = (32kt+8q+j == 16(2w+u)+nl)
    bf8 bfr[2][2];
    #pragma unroll
    for (int kt = 0; kt < 2; ++kt)
        #pragma unroll
        for (int u = 0; u < 2; ++u) {
            bf8 v;
            #pragma unroll
            for (int j = 0; j < 8; ++j)
                v[j] = (short)((32 * kt + 8 * q + j == 16 * (2 * w + u) + nl) ? 0x3F80 : 0);
            bfr[kt][u] = v;
        }

    const int t0 = 1 + 64 * c;
    const int nsteps = (c == 15) ? 63 : 64;
    const float* emb = em + (size_t)b * T * 64;

    int tl = t0 + lane; if (tl > T - 1) tl = T - 1;
    const int yvl = yg[b * T + tl];
    const unsigned long long msk = __ballot(lane < nsteps && yvl != 0);

    float ldc = emb[t0 * 64 + lane];              // emission prefetch (1 deep)
    for (int s = 0; s < nsteps; ++s) {
        int tn = t0 + s + 1; if (tn > T - 1) tn = T - 1;
        const float ldn = emb[tn * 64 + lane];
        if ((msk >> s) & 1ull) {                  // wave-uniform; active ~98.4%
            d_sh[w][lane] = exp2f(ldc * LOG2E - 7.0f);   // d[state=lane]
            // d pairs for tile mt regs r: rows g(mt,4q+r) ->
            // d_sh[w][32(mt>>1) + 4(mt&1) + 8q + r]  (broadcast; per-wave DS
            // pipe is in-order, so write->read needs no barrier)
            f2 dp[4][2];
            #pragma unroll
            for (int mt = 0; mt < 4; ++mt) {
                const float* dsrc = &d_sh[w][32 * (mt >> 1) + 4 * (mt & 1) + 8 * q];
                dp[mt][0] = *(const f2*)&dsrc[0];
                dp[mt][1] = *(const f2*)&dsrc[2];
            }
            // my two column tiles: 4 output tiles each, 2-deep K=64 chains
            #pragma unroll
            for (int u = 0; u < 2; ++u) {
                f4 acc[4];
                #pragma unroll
                for (int mt = 0; mt < 4; ++mt) {
                    f4 a = __builtin_amdgcn_mfma_f32_16x16x32_bf16(
                               afr[mt][0], bfr[0][u], (f4)(0.0f), 0, 0, 0);
                    acc[mt] = __builtin_amdgcn_mfma_f32_16x16x32_bf16(
                               afr[mt][1], bfr[1][u], a, 0, 0, 0);
                }
                // scale rows by d (packed f32 mul), pack:
                // tile mt -> bfr[mt>>1][u], dword-half mt&1
                #pragma unroll
                for (int kt = 0; kt < 2; ++kt) {
                    f2 a0, a1, b0, b1;
                    a0[0] = acc[2*kt  ][0]; a0[1] = acc[2*kt  ][1];
                    a1[0] = acc[2*kt  ][2]; a1[1] = acc[2*kt  ][3];
                    b0[0] = acc[2*kt+1][0]; b0[1] = acc[2*kt+1][1];
                    b1[0] = acc[2*kt+1][2]; b1[1] = acc[2*kt+1][3];
                    a0 *= dp[2*kt  ][0];  a1 *= dp[2*kt  ][1];   // v_pk_mul_f32
                    b0 *= dp[2*kt+1][0];  b1 *= dp[2*kt+1][1];
                    union { uint4 uu; bf8 v8; } wv;
                    wv.uu.x = pack_bf_trunc(a0[0], a0[1]);
                    wv.uu.y = pack_bf_trunc(a1[0], a1[1]);
                    wv.uu.z = pack_bf_trunc(b0[0], b0[1]);
                    wv.uu.w = pack_bf_trunc(b1[0], b1[1]);
                    bfr[kt][u] = wv.v8;
                }
            }
        }
        ldc = ldn;
    }

    // ---- dump my P^T slice: Pg[(b*16+c)*4096 + n*64 + i] = P_c[i][n],
    //      n = 16(2w+u)+nl, i = 32kt+8q+j (j contiguous -> 16B stores) ----
    unsigned short* pg = Pg + ((size_t)(b * 16 + c) << 12);
    #pragma unroll
    for (int u = 0; u < 2; ++u)
        #pragma unroll
        for (int kt = 0; kt < 2; ++kt)
            *(uint4*)(pg + (16 * (2 * w + u) + nl) * 64 + 32 * kt + 8 * q) =
                *(const uint4*)&bfr[kt][u];
}

// ============================================================================
// Kernel 2: per-batch combine, 4 waves/block (unchanged from round-3).
//   wave 0 : v = P_15 ... P_0 * exp(e0 - M0) with 1-chunk-ahead double-buffered
//            P prefetch, exact-pow2 re-centering per chunk.
//   waves 1-3 : gather scores (emission + transition) + masked-step count.
// ============================================================================
__global__ __attribute__((amdgpu_flat_work_group_size(256, 256)))
void crf_combine(const int* __restrict__ yg, const float* __restrict__ em,
                 const float* __restrict__ tr, const unsigned short* __restrict__ Pg,
                 float* __restrict__ out)
{
    constexpr int T = 1024;
    const int b = blockIdx.x, tid = threadIdx.x;
    const int w = tid >> 6, j = tid & 63;

    __shared__ __align__(16) float v_sh[64];
    __shared__ float red[3][4];

    float ep = 0.f, tp = 0.f; int cnt = 0;
    float v = 0.f, L = 0.f, vs = 0.f;

    if (w == 0) {
        const float e0 = em[(size_t)b * T * 64 + j];
        float M0 = e0;
        #pragma unroll
        for (int o = 32; o > 0; o >>= 1) M0 = fmaxf(M0, __shfl_xor(M0, o, 64));
        v = exp2f((e0 - M0) * LOG2E);
        L = M0;

        const unsigned short* row = Pg + ((size_t)(b * 16) << 12) + j * 64; // col j of P_c
        uint4 pA[8], pB[8];
        #pragma unroll
        for (int r = 0; r < 8; ++r) pA[r] = *(const uint4*)(row + r * 8);

#define CHUNK_STEP(CUR, NXT, CIDX)                                                 \
        do {                                                                       \
            if ((CIDX) + 1 < 16) {  /* prefetch next chunk: independent of v */    \
                const unsigned short* rn = row + ((size_t)((CIDX) + 1) << 12);     \
                _Pragma("unroll")                                                  \
                for (int r = 0; r < 8; ++r) NXT[r] = *(const uint4*)(rn + r * 8);  \
            }                                                                      \
            v_sh[j] = v;                            /* single wave: in-order DS */ \
            float s0 = 0.f, s1 = 0.f, s2 = 0.f, s3 = 0.f;                          \
            _Pragma("unroll")                                                      \
            for (int r = 0; r < 8; ++r) {                                          \
                const uint4 qq = CUR[r];                                           \
                const float* vp = &v_sh[r * 8];                                    \
                s0 = fmaf(__uint_as_float(qq.x << 16),         vp[0], s0);         \
                s1 = fmaf(__uint_as_float(qq.x & 0xFFFF0000u), vp[1], s1);         \
                s2 = fmaf(__uint_as_float(qq.y << 16),         vp[2], s2);         \
                s3 = fmaf(__uint_as_float(qq.y & 0xFFFF0000u), vp[3], s3);         \
                s0 = fmaf(__uint_as_float(qq.z << 16),         vp[4], s0);         \
                s1 = fmaf(__uint_as_float(qq.z & 0xFFFF0000u), vp[5], s1);         \
                s2 = fmaf(__uint_as_float(qq.w << 16),         vp[6], s2);         \
                s3 = fmaf(__uint_as_float(qq.w & 0xFFFF0000u), vp[7], s3);         \
            }                                                                      \
            float s = (s0 + s1) + (s2 + s3);                                       \
            const unsigned sb =                                                    \
                (unsigned)__builtin_amdgcn_readlane((int)__float_as_uint(s), 0);   \
            const int ef = (int)((sb >> 23) & 0xFF);                               \
            if (ef > 0 && ef < 255 && ef != 127) {  /* exact-pow2 re-center */     \
                const int E = ef - 127;                                            \
                s *= __uint_as_float((unsigned)(127 - E) << 23);                   \
                L += (float)E * LN2;                                               \
            }                                                                      \
            v = s;                                                                 \
        } while (0)

        for (int cc = 0; cc < 16; cc += 2) {
            CHUNK_STEP(pA, pB, cc);
            CHUNK_STEP(pB, pA, cc + 1);
        }
#undef CHUNK_STEP

        vs = v;
        #pragma unroll
        for (int o = 32; o > 0; o >>= 1) vs += __shfl_xor(vs, o, 64);
    } else {
        // ---- scores + unmasked-step count, waves 1..3 (stride 192 over t) ----
        const int* yb = yg + b * T;
        const int wt = tid - 64;                      // 0..191
        for (int t = 1 + wt; t < T; t += 192) {
            const int yt = yb[t];
            if (yt != 0) {
                ++cnt;
                tp += tr[yb[t - 1] * 64 + yt];
                ep += em[((size_t)b * T + t) * 64 + yt];
            }
        }
        if (tid == 64) {
            const int y0 = yb[0];
            if (y0 != 0) ep += em[(size_t)b * T * 64 + y0];
        }
        #pragma unroll
        for (int o = 32; o > 0; o >>= 1) {
            ep  += __shfl_xor(ep, o, 64);
            tp  += __shfl_xor(tp, o, 64);
            cnt += __shfl_xor(cnt, o, 64);
        }
        if (j == 0) { red[0][w] = ep; red[1][w] = tp; red[2][w] = (float)cnt; }
    }
    __syncthreads();

    if (tid == 0) {
        const float eps = red[0][1] + red[0][2] + red[0][3];
        const float tps = red[1][1] + red[1][2] + red[1][3];
        const float cs  = red[2][1] + red[2][2] + red[2][3];
        const float logz = L + 7.0f * LN2 * cs + __log2f(vs) * LN2;
        atomicAdd(out, (eps + tps - logz) * (-1.0f / 256.0f));
    }
}

extern "C" void kernel_launch(void* const* d_in, const int* in_sizes, int n_in,
                              void* d_out, int out_size, void* d_ws, size_t ws_size,
                              hipStream_t stream) {
    const int*   y  = (const int*)d_in[0];
    const float* em = (const float*)d_in[1];
    const float* tr = (const float*)d_in[2];
    float* out = (float*)d_out;
    unsigned short* Pg = (unsigned short*)d_ws;   // needs 256*16*4096*2 = 32 MB

    hipMemsetAsync(out, 0, sizeof(float), stream);
    crf_scan<<<dim3(16, 256), dim3(128), 0, stream>>>(y, em, tr, Pg);
    crf_combine<<<dim3(256), dim3(256), 0, stream>>>(y, em, tr, Pg, out);
}

// Round 7
// 207.316 us; speedup vs baseline: 1.1825x; 1.0886x over previous
//
#include <hip/hip_runtime.h>

#define LOG2E 1.44269504088896340736f
#define LN2   0.69314718055994530942f

typedef short bf8 __attribute__((ext_vector_type(8)));   // 8 bf16 = one 16x16x32 A/B frag (4 VGPRs)
typedef float f4  __attribute__((ext_vector_type(4)));   // 4 f32  = one 16x16 C/D frag
typedef float f2  __attribute__((ext_vector_type(2)));   // packed f32 pair -> v_pk_mul_f32

static __device__ __forceinline__ unsigned short f2bf_rne(float f) {
    unsigned u = __float_as_uint(f);
    u += 0x7FFFu + ((u >> 16) & 1u);
    return (unsigned short)(u >> 16);
}
// pack two f32 -> two bf16 (truncation; same numerics as all passing rounds)
static __device__ __forceinline__ unsigned pack_bf_trunc(float lo, float hi) {
    return __builtin_amdgcn_perm(__float_as_uint(hi), __float_as_uint(lo), 0x07060302u);
}

// MFMA via inline asm with "v" constraints: forces A, B, C, D into ARCH VGPRs.
// The builtin path let the register allocator pick the AGPR form, which added
// ~100 v_accvgpr_read/write per step (the 4x VALU inflation seen in r3-r5
// counters: VGPR_Count 40-60 against a ~90-reg working set).
static __device__ __forceinline__ f4 mfma_v(bf8 a, bf8 b, f4 c) {
    f4 d;
    asm volatile("v_mfma_f32_16x16x32_bf16 %0, %1, %2, %3"
                 : "=v"(d) : "v"(a), "v"(b), "v"(c));
    return d;
}
// MFMA -> VALU-read-of-D hazard fence (worst case 18 wait states on CDNA) +
// sched_barrier(0) so the compiler cannot hoist register-only reads across
// the nops (inline-asm "memory" does NOT order register ops — rule #18).
static __device__ __forceinline__ void acc_fence() {
    __builtin_amdgcn_sched_barrier(0);
    asm volatile("s_nop 7\ns_nop 7\ns_nop 7");
    __builtin_amdgcn_sched_barrier(0);
}

// ============================================================================
// Kernel 1: per-(batch, 64-step chunk) operator product, P fully in registers,
// 16x16x32 bf16 MFMA (asm, arch-VGPR form), one wave per chunk (r3 structure).
//
//   Op_t = mask_t ? D_t * M^T : I,  D_t = diag(exp(em_t) * 2^-7), M = exp(tr)
//   P_c  = Op_{t0+63} ... Op_{t0}   (64x64), dumped bf16 as P^T.
//
// Layout (verified r3/r4/r5, absmax 0): B-frag bfr[kt][nt][j] = P[32kt+8q+j]
// [16nt+nl]; MFMA output tile mt maps to global rows g(mt, m=4q+r) =
// 32(mt>>1)+8q+4(mt&1)+r, so tile mt's scaled/packed output IS dword-half
// (mt&1) of bfr[mt>>1][nt] in the same lane (row permutation folded into the
// A-fragments at setup, free).
//
// Matrix-pipe floor: 8064 MFMA/SIMD x 16.1 cy = ~133k cy = 55 us — measured
// matrix-busy equals this in EVERY round; this round removes the serialized
// VALU on top of it (accvgpr moves) and adds setprio so the pipe stays fed.
// ============================================================================
__global__ __attribute__((amdgpu_flat_work_group_size(64, 64)))
void crf_scan(const int* __restrict__ yg, const float* __restrict__ em,
              const float* __restrict__ tr, unsigned short* __restrict__ Pg)
{
    constexpr int T = 1024;
    const int c = blockIdx.x, b = blockIdx.y;
    const int lane = threadIdx.x, nl = lane & 15, q = lane >> 4;

    __shared__ __align__(16) float d_sh[64];

    // ---- A-fragments of M^T with permuted rows (constant):
    //      afr[mt][ka], elem j: A[m=nl][k=8q+j of K-tile ka]
    //        = exp(tr[(32ka+8q+j)*64 + g(mt,nl)])
    bf8 afr[4][2];
    #pragma unroll
    for (int mt = 0; mt < 4; ++mt) {
        const int g = 32 * (mt >> 1) + 8 * (nl >> 2) + 4 * (mt & 1) + (nl & 3);
        #pragma unroll
        for (int ka = 0; ka < 2; ++ka) {
            bf8 v;
            #pragma unroll
            for (int j = 0; j < 8; ++j) {
                const int k = 32 * ka + 8 * q + j;
                v[j] = (short)f2bf_rne(exp2f(tr[k * 64 + g] * LOG2E));
            }
            afr[mt][ka] = v;
        }
    }

    // ---- P = I in B-fragments: bfr[kt][nt][j] = (32kt+8q+j == 16nt+nl) ----
    bf8 bfr[2][4];
    #pragma unroll
    for (int kt = 0; kt < 2; ++kt)
        #pragma unroll
        for (int nt = 0; nt < 4; ++nt) {
            bf8 v;
            #pragma unroll
            for (int j = 0; j < 8; ++j)
                v[j] = (short)((32 * kt + 8 * q + j == 16 * nt + nl) ? 0x3F80 : 0);
            bfr[kt][nt] = v;
        }

    const f4 zc = (f4)(0.0f);                     // persistent zero C operand

    const int t0 = 1 + 64 * c;
    const int nsteps = (c == 15) ? 63 : 64;
    const float* emb = em + (size_t)b * T * 64;

    int tl = t0 + lane; if (tl > T - 1) tl = T - 1;
    const int yvl = yg[b * T + tl];
    const unsigned long long msk = __ballot(lane < nsteps && yvl != 0);

    float ldc = emb[t0 * 64 + lane];              // emission prefetch (1 deep)
    for (int s = 0; s < nsteps; ++s) {
        int tn = t0 + s + 1; if (tn > T - 1) tn = T - 1;
        const float ldn = emb[tn * 64 + lane];
        if ((msk >> s) & 1ull) {                  // wave-uniform; active ~98.4%
            d_sh[lane] = exp2f(ldc * LOG2E - 7.0f);      // d[state=lane]
            // d pairs for tile mt regs r: rows g(mt,4q+r) ->
            // d_sh[32(mt>>1) + 4(mt&1) + 8q + r]  (broadcast; single wave =>
            // DS pipe in-order, no barrier)
            f2 dp[4][2];
            #pragma unroll
            for (int mt = 0; mt < 4; ++mt) {
                const float* dsrc = &d_sh[32 * (mt >> 1) + 4 * (mt & 1) + 8 * q];
                dp[mt][0] = *(const f2*)&dsrc[0];
                dp[mt][1] = *(const f2*)&dsrc[2];
            }
            // two half-steps: column-tile pair {2h, 2h+1}. 16 MFMAs issued
            // back-to-back (dependent pairs chain through C: 0 wait states),
            // one hazard fence, then the pack VALU for that pair.
            #pragma unroll
            for (int h = 0; h < 2; ++h) {
                f4 acc[2][4];
                __builtin_amdgcn_s_setprio(1);
                #pragma unroll
                for (int u = 0; u < 2; ++u) {
                    const int nt = 2 * h + u;
                    #pragma unroll
                    for (int mt = 0; mt < 4; ++mt) {
                        f4 t = mfma_v(afr[mt][0], bfr[0][nt], zc);
                        acc[u][mt] = mfma_v(afr[mt][1], bfr[1][nt], t);
                    }
                }
                acc_fence();
                __builtin_amdgcn_s_setprio(0);
                #pragma unroll
                for (int u = 0; u < 2; ++u) {
                    const int nt = 2 * h + u;
                    #pragma unroll
                    for (int kt = 0; kt < 2; ++kt) {
                        f2 a0, a1, b0, b1;
                        a0[0] = acc[u][2*kt  ][0]; a0[1] = acc[u][2*kt  ][1];
                        a1[0] = acc[u][2*kt  ][2]; a1[1] = acc[u][2*kt  ][3];
                        b0[0] = acc[u][2*kt+1][0]; b0[1] = acc[u][2*kt+1][1];
                        b1[0] = acc[u][2*kt+1][2]; b1[1] = acc[u][2*kt+1][3];
                        a0 *= dp[2*kt  ][0];  a1 *= dp[2*kt  ][1];   // v_pk_mul_f32
                        b0 *= dp[2*kt+1][0];  b1 *= dp[2*kt+1][1];
                        union { uint4 uu; bf8 v8; } wv;
                        wv.uu.x = pack_bf_trunc(a0[0], a0[1]);
                        wv.uu.y = pack_bf_trunc(a1[0], a1[1]);
                        wv.uu.z = pack_bf_trunc(b0[0], b0[1]);
                        wv.uu.w = pack_bf_trunc(b1[0], b1[1]);
                        bfr[kt][nt] = wv.v8;     // tile mt -> half (mt&1) of bfr[mt>>1]
                    }
                }
            }
        }
        ldc = ldn;
    }

    // ---- dump P^T: Pg[(b*16+c)*4096 + n*64 + i] = P_c[i][n],
    //      n = 16nt+nl, i = 32kt+8q+j (j contiguous -> 16B stores) ----
    unsigned short* pg = Pg + ((size_t)(b * 16 + c) << 12);
    #pragma unroll
    for (int nt = 0; nt < 4; ++nt)
        #pragma unroll
        for (int kt = 0; kt < 2; ++kt)
            *(uint4*)(pg + (16 * nt + nl) * 64 + 32 * kt + 8 * q) =
                *(const uint4*)&bfr[kt][nt];
}

// ============================================================================
// Kernel 2: per-batch combine, 4 waves/block (unchanged from round-3).
//   wave 0 : v = P_15 ... P_0 * exp(e0 - M0) with 1-chunk-ahead double-buffered
//            P prefetch, exact-pow2 re-centering per chunk.
//   waves 1-3 : gather scores (emission + transition) + masked-step count.
// ============================================================================
__global__ __attribute__((amdgpu_flat_work_group_size(256, 256)))
void crf_combine(const int* __restrict__ yg, const float* __restrict__ em,
                 const float* __restrict__ tr, const unsigned short* __restrict__ Pg,
                 float* __restrict__ out)
{
    constexpr int T = 1024;
    const int b = blockIdx.x, tid = threadIdx.x;
    const int w = tid >> 6, j = tid & 63;

    __shared__ __align__(16) float v_sh[64];
    __shared__ float red[3][4];

    float ep = 0.f, tp = 0.f; int cnt = 0;
    float v = 0.f, L = 0.f, vs = 0.f;

    if (w == 0) {
        const float e0 = em[(size_t)b * T * 64 + j];
        float M0 = e0;
        #pragma unroll
        for (int o = 32; o > 0; o >>= 1) M0 = fmaxf(M0, __shfl_xor(M0, o, 64));
        v = exp2f((e0 - M0) * LOG2E);
        L = M0;

        const unsigned short* row = Pg + ((size_t)(b * 16) << 12) + j * 64; // col j of P_c
        uint4 pA[8], pB[8];
        #pragma unroll
        for (int r = 0; r < 8; ++r) pA[r] = *(const uint4*)(row + r * 8);

#define CHUNK_STEP(CUR, NXT, CIDX)                                                 \
        do {                                                                       \
            if ((CIDX) + 1 < 16) {  /* prefetch next chunk: independent of v */    \
                const unsigned short* rn = row + ((size_t)((CIDX) + 1) << 12);     \
                _Pragma("unroll")                                                  \
                for (int r = 0; r < 8; ++r) NXT[r] = *(const uint4*)(rn + r * 8);  \
            }                                                                      \
            v_sh[j] = v;                            /* single wave: in-order DS */ \
            float s0 = 0.f, s1 = 0.f, s2 = 0.f, s3 = 0.f;                          \
            _Pragma("unroll")                                                      \
            for (int r = 0; r < 8; ++r) {                                          \
                const uint4 qq = CUR[r];                                           \
                const float* vp = &v_sh[r * 8];                                    \
                s0 = fmaf(__uint_as_float(qq.x << 16),         vp[0], s0);         \
                s1 = fmaf(__uint_as_float(qq.x & 0xFFFF0000u), vp[1], s1);         \
                s2 = fmaf(__uint_as_float(qq.y << 16),         vp[2], s2);         \
                s3 = fmaf(__uint_as_float(qq.y & 0xFFFF0000u), vp[3], s3);         \
                s0 = fmaf(__uint_as_float(qq.z << 16),         vp[4], s0);         \
                s1 = fmaf(__uint_as_float(qq.z & 0xFFFF0000u), vp[5], s1);         \
                s2 = fmaf(__uint_as_float(qq.w << 16),         vp[6], s2);         \
                s3 = fmaf(__uint_as_float(qq.w & 0xFFFF0000u), vp[7], s3);         \
            }                                                                      \
            float s = (s0 + s1) + (s2 + s3);                                       \
            const unsigned sb =                                                    \
                (unsigned)__builtin_amdgcn_readlane((int)__float_as_uint(s), 0);   \
            const int ef = (int)((sb >> 23) & 0xFF);                               \
            if (ef > 0 && ef < 255 && ef != 127) {  /* exact-pow2 re-center */     \
                const int E = ef - 127;                                            \
                s *= __uint_as_float((unsigned)(127 - E) << 23);                   \
                L += (float)E * LN2;                                               \
            }                                                                      \
            v = s;                                                                 \
        } while (0)

        for (int cc = 0; cc < 16; cc += 2) {
            CHUNK_STEP(pA, pB, cc);
            CHUNK_STEP(pB, pA, cc + 1);
        }
#undef CHUNK_STEP

        vs = v;
        #pragma unroll
        for (int o = 32; o > 0; o >>= 1) vs += __shfl_xor(vs, o, 64);
    } else {
        // ---- scores + unmasked-step count, waves 1..3 (stride 192 over t) ----
        const int* yb = yg + b * T;
        const int wt = tid - 64;                      // 0..191
        for (int t = 1 + wt; t < T; t += 192) {
            const int yt = yb[t];
            if (yt != 0) {
                ++cnt;
                tp += tr[yb[t - 1] * 64 + yt];
                ep += em[((size_t)b * T + t) * 64 + yt];
            }
        }
        if (tid == 64) {
            const int y0 = yb[0];
            if (y0 != 0) ep += em[(size_t)b * T * 64 + y0];
        }
        #pragma unroll
        for (int o = 32; o > 0; o >>= 1) {
            ep  += __shfl_xor(ep, o, 64);
            tp  += __shfl_xor(tp, o, 64);
            cnt += __shfl_xor(cnt, o, 64);
        }
        if (j == 0) { red[0][w] = ep; red[1][w] = tp; red[2][w] = (float)cnt; }
    }
    __syncthreads();

    if (tid == 0) {
        const float eps = red[0][1] + red[0][2] + red[0][3];
        const float tps = red[1][1] + red[1][2] + red[1][3];
        const float cs  = red[2][1] + red[2][2] + red[2][3];
        const float logz = L + 7.0f * LN2 * cs + __log2f(vs) * LN2;
        atomicAdd(out, (eps + tps - logz) * (-1.0f / 256.0f));
    }
}

extern "C" void kernel_launch(void* const* d_in, const int* in_sizes, int n_in,
                              void* d_out, int out_size, void* d_ws, size_t ws_size,
                              hipStream_t stream) {
    const int*   y  = (const int*)d_in[0];
    const float* em = (const float*)d_in[1];
    const float* tr = (const float*)d_in[2];
    float* out = (float*)d_out;
    unsigned short* Pg = (unsigned short*)d_ws;   // needs 256*16*4096*2 = 32 MB

    hipMemsetAsync(out, 0, sizeof(float), stream);
    crf_scan<<<dim3(16, 256), dim3(64), 0, stream>>>(y, em, tr, Pg);
    crf_combine<<<dim3(256), dim3(256), 0, stream>>>(y, em, tr, Pg, out);
}